// Round 1
// 239.211 us; speedup vs baseline: 1.0401x; 1.0401x over previous
//
#include <hip/hip_runtime.h>
#include <cstdint>
#include <cstddef>

#define N_NODES 50000
#define N_EDGES 1600000
#define TOT_E   (N_EDGES + N_NODES)
#define IN_DIM  256
#define HC      128
#define NHEAD   4
#define OUT_DIM 64

// bucket-radix CSR build (fixed-stride buckets)
#define SHIFT   7
#define BSZ     128
#define NBUK    ((N_NODES + BSZ - 1) / BSZ)      // 391
#define CHUNK   2048
#define EPT     8                                // CHUNK / 256
#define NCHUNK  ((TOT_E + CHUNK - 1) / CHUNK)    // 806
#define CAP     6144                             // bucket cap (mean 4220, +29 sd)
#define QCAP    1792                             // quarter-bucket cap (mean 1088, +21 sd)

// k1 MFMA tiling
#define XPAD 264   // bf16 elems per LDS row (256 + 8)
#define HPAD 132   // fp32 elems per LDS row in epilogue (128 + 4)
#define K1_NB ((N_NODES + 63) / 64)              // 782

#define W2_GEMM_BLK ((HC * IN_DIM) / 256)        // 128 blocks for wt prep
#define W2_LIN_BLK  ((OUT_DIM * HC) / 256)       // 32 blocks for lin_W prep

typedef __attribute__((ext_vector_type(8))) short bf16x8;
typedef __attribute__((ext_vector_type(4))) float f32x4;
typedef __attribute__((ext_vector_type(4))) unsigned short u16x4;

static __device__ __forceinline__ uint16_t f2bf(float f) {
    uint32_t u = __float_as_uint(f);
    uint32_t r = (u + 0x7fffu + ((u >> 16) & 1u)) >> 16;   // RNE
    return (uint16_t)r;
}
static __device__ __forceinline__ float bf_lo(uint32_t u) {
    return __uint_as_float(u << 16);
}
static __device__ __forceinline__ float bf_hi(uint32_t u) {
    return __uint_as_float(u & 0xffff0000u);
}

// ---------------------------------------------------------------------------
// W prep: W fp32 [256][128] -> W^T bf16 [128][256]; lin_W fp32 [128][64] ->
// lin_W^T split-bf16 (hi+lo pair, error ~2^-17 so k7 keeps f32 accuracy);
// also zeroes gcur (folds the memset dispatch).
// ---------------------------------------------------------------------------
__global__ __launch_bounds__(256) void w2bf(const float* __restrict__ W,
                                            const float* __restrict__ linW,
                                            uint16_t* __restrict__ wt,
                                            uint16_t* __restrict__ lwt,
                                            int* __restrict__ gcur) {
    if (blockIdx.x < W2_GEMM_BLK) {
        int idx = blockIdx.x * 256 + threadIdx.x;   // n*256 + k
        int n = idx >> 8, k = idx & 255;
        wt[idx] = f2bf(W[(size_t)k * HC + n]);
        if (idx < NBUK) gcur[idx] = 0;
    } else {
        int idx = (blockIdx.x - W2_GEMM_BLK) * 256 + threadIdx.x;  // n*128 + k
        int n = idx >> 7, k = idx & 127;
        float w = linW[(size_t)k * OUT_DIM + n];
        uint16_t h = f2bf(w);
        float hf = __uint_as_float((uint32_t)h << 16);
        lwt[idx] = h;                               // hi half
        lwt[OUT_DIM * HC + idx] = f2bf(w - hf);     // lo residual
    }
}

// ---------------------------------------------------------------------------
// K1P3 (grid-fused): blocks [0, K1_NB) run the MFMA GEMM (h=x@W bf16 +
// fused a_src/a_dst); blocks [K1_NB, K1_NB+NCHUNK) run the edge binning.
// ---------------------------------------------------------------------------
__global__ __launch_bounds__(256) void k1p3(const float* __restrict__ x,
                                            const uint16_t* __restrict__ wt,
                                            const float* __restrict__ att_src,
                                            const float* __restrict__ att_dst,
                                            uint16_t* __restrict__ hb,
                                            float* __restrict__ a_src,
                                            float* __restrict__ a_dst,
                                            const int* __restrict__ ei,
                                            int* __restrict__ gcur,
                                            uint32_t* __restrict__ binned) {
    __shared__ char smem[64 * 528];   // k1: xs(bf16 64x264)==hs(f32 64x132); p3: hist+lcur
    __shared__ float att_s[HC], att_d[HC];
    const int tid = threadIdx.x;

    if (blockIdx.x < K1_NB) {
        // ---------------- k1: MFMA GEMM ----------------
        uint16_t* xs = (uint16_t*)smem;
        float*    hs = (float*)smem;
        const int wave = tid >> 6;
        const int lane = tid & 63;
        const int m    = lane & 15;
        const int q    = lane >> 4;
        const int row0 = blockIdx.x * 64;

        if (tid < HC) { att_s[tid] = att_src[tid]; att_d[tid] = att_dst[tid]; }

        for (int i = tid * 4; i < 64 * IN_DIM; i += 1024) {
            int r = i >> 8, c = i & 255;
            int gr = row0 + r;
            float4 v = make_float4(0.f, 0.f, 0.f, 0.f);
            if (gr < N_NODES) v = *(const float4*)(x + (size_t)gr * IN_DIM + c);
            uint32_t lo = (uint32_t)f2bf(v.x) | ((uint32_t)f2bf(v.y) << 16);
            uint32_t hi = (uint32_t)f2bf(v.z) | ((uint32_t)f2bf(v.w) << 16);
            *(uint2*)(xs + r * XPAD + c) = make_uint2(lo, hi);
        }
        __syncthreads();

        f32x4 acc[8];
        #pragma unroll
        for (int t = 0; t < 8; ++t) acc[t] = (f32x4){0.f, 0.f, 0.f, 0.f};

        const int arow = wave * 16 + m;
        #pragma unroll
        for (int ks = 0; ks < IN_DIM; ks += 32) {
            bf16x8 a = *(const bf16x8*)(xs + arow * XPAD + ks + q * 8);
            #pragma unroll
            for (int t = 0; t < 8; ++t) {
                bf16x8 b = *(const bf16x8*)(wt + (size_t)(t * 16 + m) * IN_DIM + ks + q * 8);
                acc[t] = __builtin_amdgcn_mfma_f32_16x16x32_bf16(a, b, acc[t], 0, 0, 0);
            }
        }
        __syncthreads();

        // C/D: col = lane&15, row = (lane>>4)*4 + reg
        #pragma unroll
        for (int t = 0; t < 8; ++t)
            #pragma unroll
            for (int r = 0; r < 4; ++r)
                hs[(wave * 16 + q * 4 + r) * HPAD + t * 16 + m] = acc[t][r];
        __syncthreads();

        for (int i = tid * 4; i < 64 * HC; i += 1024) {
            int r = i >> 7, c = i & 127;
            if (row0 + r < N_NODES) {
                float4 v = *(const float4*)(hs + r * HPAD + c);
                uint32_t lo = (uint32_t)f2bf(v.x) | ((uint32_t)f2bf(v.y) << 16);
                uint32_t hi = (uint32_t)f2bf(v.z) | ((uint32_t)f2bf(v.w) << 16);
                *(uint2*)(hb + (size_t)(row0 + r) * HC + c) = make_uint2(lo, hi);
            }
        }
        {
            int r = tid >> 2, hd = tid & 3;
            if (row0 + r < N_NODES) {
                float s = 0.f, d = 0.f;
                #pragma unroll
                for (int j = 0; j < 32; ++j) {
                    float v = hs[r * HPAD + hd * 32 + j];
                    s = fmaf(v, att_s[hd * 32 + j], s);
                    d = fmaf(v, att_d[hd * 32 + j], d);
                }
                a_src[(row0 + r) * NHEAD + hd] = s;
                a_dst[(row0 + r) * NHEAD + hd] = d;
            }
        }
    } else {
        // ---------------- p3: bin edges into fixed-stride bucket regions ----
        int* hist = (int*)smem;
        int* lcur = hist + NBUK;
        for (int i = tid; i < NBUK; i += 256) hist[i] = 0;
        __syncthreads();

        uint32_t wreg[EPT];
        const int base = (blockIdx.x - K1_NB) * CHUNK;
        #pragma unroll
        for (int k = 0; k < EPT; ++k) {
            int e = base + k * 256 + tid;
            uint32_t word = 0xFFFFFFFFu;
            if (e < TOT_E) {
                int src, dst;
                if (e < N_EDGES) { src = ei[e]; dst = ei[N_EDGES + e]; }
                else             { src = e - N_EDGES; dst = src; }
                int b = dst >> SHIFT;
                word = (uint32_t)src | ((uint32_t)(dst & (BSZ - 1)) << 16)
                     | ((uint32_t)b << 23);
                atomicAdd(&hist[b], 1);
            }
            wreg[k] = word;
        }
        __syncthreads();
        for (int i = tid; i < NBUK; i += 256) {
            int c = hist[i];
            lcur[i] = c ? atomicAdd(&gcur[i], c) : 0;   // within-bucket base
        }
        __syncthreads();
        #pragma unroll
        for (int k = 0; k < EPT; ++k) {
            uint32_t word = wreg[k];
            if (word != 0xFFFFFFFFu) {
                int b = (int)(word >> 23);
                int pos = atomicAdd(&lcur[b], 1);
                if (pos < CAP) binned[(size_t)b * CAP + pos] = word;
            }
        }
    }
}

// ---------------------------------------------------------------------------
// Q4 (fused p4+k6): 4 quarter-blocks per bucket. Stream the bucket's binned
// region, keep this quarter's edges in LDS (append -> count -> scan ->
// regroup), then gather.
//
// Gather restructure: 16 lanes per node, 4 nodes per wave concurrently
// (8 ch/lane, uint4 h-row loads). One unrolled iteration retires 16 edges
// (4 per node) instead of 4, with ~the same wave instruction count:
//   - srcs stored as u16 in ew2, read 4-at-a-time with ONE aligned
//     ds_read_b64 (nbeg padded to a multiple of 4 in the scan)
//   - a_dst hoisted out of the loop (constant per lane per node)
//   - leaky/exp redundancy drops from 16 lanes/head to 4
// ---------------------------------------------------------------------------
__global__ __launch_bounds__(256) void q4_agg(const uint32_t* __restrict__ binned,
                                              const int* __restrict__ gcur,
                                              const uint32_t* __restrict__ hb32,
                                              const float* __restrict__ a_src,
                                              const float* __restrict__ a_dst,
                                              const float* __restrict__ bias,
                                              uint32_t* __restrict__ actb) {
    __shared__ uint32_t ewb[QCAP];       // 7 KB: unordered append of this quarter's edges
    __shared__ uint16_t ew2[QCAP * 2];   // 7 KB: srcs grouped by local node (2x pad for safe overread)
    __shared__ int ncnt[32], nbeg[32], ncur[32];
    __shared__ int tot;
    const int b   = blockIdx.x >> 2;
    const int sub = blockIdx.x & 3;
    const int tid = threadIdx.x;

    int cnt = gcur[b];
    if (cnt > CAP) cnt = CAP;
    if (tid == 0) tot = 0;
    if (tid < 32) ncnt[tid] = 0;
    __syncthreads();

    const uint32_t* bb = binned + (size_t)b * CAP;
    for (int i = tid; i < cnt; i += 256) {
        uint32_t word = bb[i];
        int dl = (word >> 16) & 127;
        if ((dl >> 5) == sub) {
            int pos = atomicAdd(&tot, 1);
            if (pos < QCAP) ewb[pos] = word;
            atomicAdd(&ncnt[dl & 31], 1);
        }
    }
    __syncthreads();
    int T = tot;
    if (T > QCAP) T = QCAP;

    if (tid < 32) {                       // inclusive scan of counts padded to x4
        int v  = ncnt[tid];
        int v4 = (v + 3) & ~3;            // pad region so nbeg is 8B-aligned (b64 reads)
        int inc = v4;
        #pragma unroll
        for (int d = 1; d < 32; d <<= 1) {
            int t = __shfl_up(inc, d, 64);
            if (tid >= d) inc += t;
        }
        nbeg[tid] = inc - v4;
        ncur[tid] = inc - v4;
    }
    __syncthreads();
    for (int i = tid; i < T; i += 256) {
        uint32_t word = ewb[i];
        int ln  = (word >> 16) & 31;
        int pos = atomicAdd(&ncur[ln], 1);
        ew2[pos] = (uint16_t)(word & 0xFFFFu);    // src only (< 50000 fits u16)
    }
    __syncthreads();

    // gather: wave w handles nodes w*8 .. w*8+7 in 2 passes of 4-at-a-time
    const int wave = tid >> 6;
    const int lane = tid & 63;
    const int g    = lane >> 4;          // node sub-group within wave
    const int sl   = lane & 15;          // channel sublane: ch [sl*8, sl*8+8)
    const int head = sl >> 2;
    const char*  hb8 = (const char*)hb32 + sl * 16;
    const float* ash = a_src + head;
    const float4 bA = *(const float4*)(bias + sl * 8);
    const float4 bB = *(const float4*)(bias + sl * 8 + 4);

    for (int pass = 0; pass < 2; ++pass) {
        const int ln   = wave * 8 + pass * 4 + g;
        const int node = b * BSZ + sub * 32 + ln;
        const int myc  = ncnt[ln];
        const int p0   = nbeg[ln];
        int m1   = max(myc, __shfl_xor(myc, 16, 64));
        int maxc = max(m1,  __shfl_xor(m1, 32, 64));
        // a_dst overread for OOB node stays inside workspace; value unused (w=0)
        const float ad = a_dst[min(node, N_NODES - 1) * NHEAD + head];

        float l = 0.f;
        float acc[8];
        #pragma unroll
        for (int j = 0; j < 8; ++j) acc[j] = 0.f;

        for (int i = 0; i < maxc; i += 4) {
            u16x4 sv = *(const u16x4*)(&ew2[p0 + i]);   // 1 ds_read_b64 = 4 srcs
            const int s0 = sv[0], s1 = sv[1], s2 = sv[2], s3 = sv[3];
            float as0 = ash[s0 * NHEAD];
            float as1 = ash[s1 * NHEAD];
            float as2 = ash[s2 * NHEAD];
            float as3 = ash[s3 * NHEAD];
            uint4 h0 = *(const uint4*)(hb8 + ((uint32_t)s0 << 8));
            uint4 h1 = *(const uint4*)(hb8 + ((uint32_t)s1 << 8));
            uint4 h2 = *(const uint4*)(hb8 + ((uint32_t)s2 << 8));
            uint4 h3 = *(const uint4*)(hb8 + ((uint32_t)s3 << 8));
            float e0 = as0 + ad, e1 = as1 + ad, e2 = as2 + ad, e3 = as3 + ad;
            e0 = fmaxf(e0, 0.2f * e0);
            e1 = fmaxf(e1, 0.2f * e1);
            e2 = fmaxf(e2, 0.2f * e2);
            e3 = fmaxf(e3, 0.2f * e3);
            float w0 = __expf(e0), w1 = __expf(e1);
            float w2 = __expf(e2), w3 = __expf(e3);
            w0 = (i + 0 < myc) ? w0 : 0.f;
            w1 = (i + 1 < myc) ? w1 : 0.f;
            w2 = (i + 2 < myc) ? w2 : 0.f;
            w3 = (i + 3 < myc) ? w3 : 0.f;
            l += (w0 + w1) + (w2 + w3);
            acc[0] = fmaf(w0, bf_lo(h0.x), acc[0]); acc[0] = fmaf(w1, bf_lo(h1.x), acc[0]);
            acc[0] = fmaf(w2, bf_lo(h2.x), acc[0]); acc[0] = fmaf(w3, bf_lo(h3.x), acc[0]);
            acc[1] = fmaf(w0, bf_hi(h0.x), acc[1]); acc[1] = fmaf(w1, bf_hi(h1.x), acc[1]);
            acc[1] = fmaf(w2, bf_hi(h2.x), acc[1]); acc[1] = fmaf(w3, bf_hi(h3.x), acc[1]);
            acc[2] = fmaf(w0, bf_lo(h0.y), acc[2]); acc[2] = fmaf(w1, bf_lo(h1.y), acc[2]);
            acc[2] = fmaf(w2, bf_lo(h2.y), acc[2]); acc[2] = fmaf(w3, bf_lo(h3.y), acc[2]);
            acc[3] = fmaf(w0, bf_hi(h0.y), acc[3]); acc[3] = fmaf(w1, bf_hi(h1.y), acc[3]);
            acc[3] = fmaf(w2, bf_hi(h2.y), acc[3]); acc[3] = fmaf(w3, bf_hi(h3.y), acc[3]);
            acc[4] = fmaf(w0, bf_lo(h0.z), acc[4]); acc[4] = fmaf(w1, bf_lo(h1.z), acc[4]);
            acc[4] = fmaf(w2, bf_lo(h2.z), acc[4]); acc[4] = fmaf(w3, bf_lo(h3.z), acc[4]);
            acc[5] = fmaf(w0, bf_hi(h0.z), acc[5]); acc[5] = fmaf(w1, bf_hi(h1.z), acc[5]);
            acc[5] = fmaf(w2, bf_hi(h2.z), acc[5]); acc[5] = fmaf(w3, bf_hi(h3.z), acc[5]);
            acc[6] = fmaf(w0, bf_lo(h0.w), acc[6]); acc[6] = fmaf(w1, bf_lo(h1.w), acc[6]);
            acc[6] = fmaf(w2, bf_lo(h2.w), acc[6]); acc[6] = fmaf(w3, bf_lo(h3.w), acc[6]);
            acc[7] = fmaf(w0, bf_hi(h0.w), acc[7]); acc[7] = fmaf(w1, bf_hi(h1.w), acc[7]);
            acc[7] = fmaf(w2, bf_hi(h2.w), acc[7]); acc[7] = fmaf(w3, bf_hi(h3.w), acc[7]);
        }

        if (node < N_NODES) {
            const float inv = 1.f / l;        // self loop => l > 0
            float o[8];
            o[0] = fmaf(acc[0], inv, bA.x); o[1] = fmaf(acc[1], inv, bA.y);
            o[2] = fmaf(acc[2], inv, bA.z); o[3] = fmaf(acc[3], inv, bA.w);
            o[4] = fmaf(acc[4], inv, bB.x); o[5] = fmaf(acc[5], inv, bB.y);
            o[6] = fmaf(acc[6], inv, bB.z); o[7] = fmaf(acc[7], inv, bB.w);
            #pragma unroll
            for (int j = 0; j < 8; ++j)
                o[j] = (o[j] > 0.f) ? o[j] : (__expf(o[j]) - 1.f);
            uint4 pk;
            pk.x = (uint32_t)f2bf(o[0]) | ((uint32_t)f2bf(o[1]) << 16);
            pk.y = (uint32_t)f2bf(o[2]) | ((uint32_t)f2bf(o[3]) << 16);
            pk.z = (uint32_t)f2bf(o[4]) | ((uint32_t)f2bf(o[5]) << 16);
            pk.w = (uint32_t)f2bf(o[6]) | ((uint32_t)f2bf(o[7]) << 16);
            *(uint4*)(actb + (size_t)node * 64 + sl * 4) = pk;
        }
    }
}

// ---------------------------------------------------------------------------
// K7: out = act @ lin_W + lin_b   [N,128] @ [128,64] via MFMA.
// act (actb) is already exact bf16; lin_W is split hi+lo bf16 so the product
// keeps f32 accuracy (hi+lo error ~2^-17). 32 MFMA/wave replaces the old
// 512 scalar fma + 160 ds_read_b128 per thread (was LDS-read-bound).
// ---------------------------------------------------------------------------
__global__ __launch_bounds__(256) void k7_out(const uint16_t* __restrict__ ab,
                                              const uint16_t* __restrict__ lwt,
                                              const float* __restrict__ linb,
                                              float* __restrict__ out) {
    __shared__ uint16_t as_[64][136];    // 64 rows x 128 bf16 (+8 pad; 272B row = 17x16B)
    const int tid  = threadIdx.x;
    const int row0 = blockIdx.x * 64;

    for (int i = tid; i < 64 * 16; i += 256) {   // 16 KB stage, 4 uint4/thread
        int r = i >> 4, cw = i & 15;
        int node = row0 + r;
        uint4 v = make_uint4(0, 0, 0, 0);
        if (node < N_NODES) v = *(const uint4*)(ab + (size_t)node * HC + cw * 8);
        *(uint4*)(&as_[r][cw * 8]) = v;
    }
    __syncthreads();

    const int wave = tid >> 6;
    const int lane = tid & 63;
    const int m    = lane & 15;
    const int q    = lane >> 4;
    const uint16_t* lwlo = lwt + OUT_DIM * HC;

    f32x4 acc[4];
    #pragma unroll
    for (int t = 0; t < 4; ++t) acc[t] = (f32x4){0.f, 0.f, 0.f, 0.f};

    const int arow = wave * 16 + m;
    #pragma unroll
    for (int ks = 0; ks < HC; ks += 32) {
        bf16x8 a = *(const bf16x8*)(&as_[arow][ks + q * 8]);
        #pragma unroll
        for (int t = 0; t < 4; ++t) {
            bf16x8 bh = *(const bf16x8*)(lwt  + (size_t)(t * 16 + m) * HC + ks + q * 8);
            bf16x8 bl = *(const bf16x8*)(lwlo + (size_t)(t * 16 + m) * HC + ks + q * 8);
            acc[t] = __builtin_amdgcn_mfma_f32_16x16x32_bf16(a, bh, acc[t], 0, 0, 0);
            acc[t] = __builtin_amdgcn_mfma_f32_16x16x32_bf16(a, bl, acc[t], 0, 0, 0);
        }
    }

    // C/D: col = lane&15, row = (lane>>4)*4 + reg
    const int grow = row0 + wave * 16 + q * 4;
    #pragma unroll
    for (int t = 0; t < 4; ++t) {
        const int col = t * 16 + m;
        const float lb = linb[col];
        #pragma unroll
        for (int r = 0; r < 4; ++r)
            if (grow + r < N_NODES)
                out[(size_t)(grow + r) * OUT_DIM + col] = acc[t][r] + lb;
    }
}

// ---------------------------------------------------------------------------
extern "C" void kernel_launch(void* const* d_in, const int* in_sizes, int n_in,
                              void* d_out, int out_size, void* d_ws, size_t ws_size,
                              hipStream_t stream) {
    (void)in_sizes; (void)n_in; (void)out_size; (void)ws_size;
    const float* x       = (const float*)d_in[0];
    const int*   ei      = (const int*)d_in[1];
    const float* W       = (const float*)d_in[2];
    const float* att_src = (const float*)d_in[3];
    const float* att_dst = (const float*)d_in[4];
    const float* bias    = (const float*)d_in[5];
    const float* linW    = (const float*)d_in[6];
    const float* linb    = (const float*)d_in[7];
    float*       out     = (float*)d_out;

    char*  ws  = (char*)d_ws;
    size_t off = 0;
    auto alloc = [&](size_t bytes) -> void* {
        void* p = ws + off;
        off += (bytes + 255) & ~(size_t)255;
        return p;
    };
    uint16_t* hb     = (uint16_t*)alloc((size_t)N_NODES * HC * 2);
    uint16_t* wt     = (uint16_t*)alloc((size_t)HC * IN_DIM * 2);
    uint32_t* actb   = (uint32_t*)alloc((size_t)N_NODES * 64 * 4);
    float*    a_src  = (float*)alloc((size_t)N_NODES * NHEAD * 4);
    float*    a_dst  = (float*)alloc((size_t)N_NODES * NHEAD * 4);
    int*      gcur   = (int*)alloc((size_t)NBUK * 4);
    uint32_t* binned = (uint32_t*)alloc((size_t)NBUK * CAP * 4);
    uint16_t* lwt    = (uint16_t*)alloc((size_t)2 * OUT_DIM * HC * 2);

    w2bf<<<W2_GEMM_BLK + W2_LIN_BLK, 256, 0, stream>>>(W, linW, wt, lwt, gcur);
    k1p3<<<K1_NB + NCHUNK, 256, 0, stream>>>(x, wt, att_src, att_dst,
                                             hb, a_src, a_dst,
                                             ei, gcur, binned);
    q4_agg<<<NBUK * 4, 256, 0, stream>>>(binned, gcur, (const uint32_t*)hb,
                                         a_src, a_dst, bias, actb);
    k7_out<<<(N_NODES + 63) / 64, 256, 0, stream>>>((const uint16_t*)actb, lwt,
                                                    linb, out);
}

// Round 2
// 235.548 us; speedup vs baseline: 1.0563x; 1.0156x over previous
//
#include <hip/hip_runtime.h>
#include <cstdint>
#include <cstddef>

#define N_NODES 50000
#define N_EDGES 1600000
#define TOT_E   (N_EDGES + N_NODES)
#define IN_DIM  256
#define HC      128
#define NHEAD   4
#define OUT_DIM 64

// bucket-radix CSR build (fixed-stride buckets)
#define SHIFT   7
#define BSZ     128
#define NBUK    ((N_NODES + BSZ - 1) / BSZ)      // 391
#define CHUNK   2048
#define EPT     8                                // CHUNK / 256
#define NCHUNK  ((TOT_E + CHUNK - 1) / CHUNK)    // 806
#define CAP     6144                             // bucket cap (mean 4220, +29 sd)
#define QCAP    1792                             // quarter-bucket cap (mean 1088, +21 sd)

// k1 MFMA tiling
#define XPAD 264   // bf16 elems per LDS row (256 + 8)
#define HPAD 132   // fp32 elems per LDS row in epilogue (128 + 4)
#define K1_NB ((N_NODES + 63) / 64)              // 782

#define W2_GEMM_BLK ((HC * IN_DIM) / 256)        // 128 blocks for wt prep
#define W2_LIN_BLK  ((OUT_DIM * HC) / 256)       // 32 blocks for lin_W prep

typedef __attribute__((ext_vector_type(8))) short bf16x8;
typedef __attribute__((ext_vector_type(4))) float f32x4;
typedef __attribute__((ext_vector_type(4))) unsigned short u16x4;

static __device__ __forceinline__ uint16_t f2bf(float f) {
    uint32_t u = __float_as_uint(f);
    uint32_t r = (u + 0x7fffu + ((u >> 16) & 1u)) >> 16;   // RNE
    return (uint16_t)r;
}
static __device__ __forceinline__ float bf_lo(uint32_t u) {
    return __uint_as_float(u << 16);
}
static __device__ __forceinline__ float bf_hi(uint32_t u) {
    return __uint_as_float(u & 0xffff0000u);
}

// ---------------------------------------------------------------------------
// W prep: W fp32 [256][128] -> W^T bf16 [128][256]; lin_W fp32 [128][64] ->
// lin_W^T split-bf16 (hi+lo pair, error ~2^-17 so k7 keeps f32 accuracy);
// also zeroes gcur (folds the memset dispatch).
// ---------------------------------------------------------------------------
__global__ __launch_bounds__(256) void w2bf(const float* __restrict__ W,
                                            const float* __restrict__ linW,
                                            uint16_t* __restrict__ wt,
                                            uint16_t* __restrict__ lwt,
                                            int* __restrict__ gcur) {
    if (blockIdx.x < W2_GEMM_BLK) {
        int idx = blockIdx.x * 256 + threadIdx.x;   // n*256 + k
        int n = idx >> 8, k = idx & 255;
        wt[idx] = f2bf(W[(size_t)k * HC + n]);
        if (idx < NBUK) gcur[idx] = 0;
    } else {
        int idx = (blockIdx.x - W2_GEMM_BLK) * 256 + threadIdx.x;  // n*128 + k
        int n = idx >> 7, k = idx & 127;
        float w = linW[(size_t)k * OUT_DIM + n];
        uint16_t h = f2bf(w);
        float hf = __uint_as_float((uint32_t)h << 16);
        lwt[idx] = h;                               // hi half
        lwt[OUT_DIM * HC + idx] = f2bf(w - hf);     // lo residual
    }
}

// ---------------------------------------------------------------------------
// K1P3 (grid-fused): blocks [0, K1_NB) run the MFMA GEMM (h=x@W bf16 +
// fused a_src/a_dst); blocks [K1_NB, K1_NB+NCHUNK) run the edge binning.
// ---------------------------------------------------------------------------
__global__ __launch_bounds__(256) void k1p3(const float* __restrict__ x,
                                            const uint16_t* __restrict__ wt,
                                            const float* __restrict__ att_src,
                                            const float* __restrict__ att_dst,
                                            uint16_t* __restrict__ hb,
                                            float* __restrict__ a_src,
                                            float* __restrict__ a_dst,
                                            const int* __restrict__ ei,
                                            int* __restrict__ gcur,
                                            uint32_t* __restrict__ binned) {
    __shared__ char smem[64 * 528];   // k1: xs(bf16 64x264)==hs(f32 64x132); p3: hist+lcur
    __shared__ float att_s[HC], att_d[HC];
    const int tid = threadIdx.x;

    if (blockIdx.x < K1_NB) {
        // ---------------- k1: MFMA GEMM ----------------
        uint16_t* xs = (uint16_t*)smem;
        float*    hs = (float*)smem;
        const int wave = tid >> 6;
        const int lane = tid & 63;
        const int m    = lane & 15;
        const int q    = lane >> 4;
        const int row0 = blockIdx.x * 64;

        if (tid < HC) { att_s[tid] = att_src[tid]; att_d[tid] = att_dst[tid]; }

        for (int i = tid * 4; i < 64 * IN_DIM; i += 1024) {
            int r = i >> 8, c = i & 255;
            int gr = row0 + r;
            float4 v = make_float4(0.f, 0.f, 0.f, 0.f);
            if (gr < N_NODES) v = *(const float4*)(x + (size_t)gr * IN_DIM + c);
            uint32_t lo = (uint32_t)f2bf(v.x) | ((uint32_t)f2bf(v.y) << 16);
            uint32_t hi = (uint32_t)f2bf(v.z) | ((uint32_t)f2bf(v.w) << 16);
            *(uint2*)(xs + r * XPAD + c) = make_uint2(lo, hi);
        }
        __syncthreads();

        f32x4 acc[8];
        #pragma unroll
        for (int t = 0; t < 8; ++t) acc[t] = (f32x4){0.f, 0.f, 0.f, 0.f};

        const int arow = wave * 16 + m;
        #pragma unroll
        for (int ks = 0; ks < IN_DIM; ks += 32) {
            bf16x8 a = *(const bf16x8*)(xs + arow * XPAD + ks + q * 8);
            #pragma unroll
            for (int t = 0; t < 8; ++t) {
                bf16x8 b = *(const bf16x8*)(wt + (size_t)(t * 16 + m) * IN_DIM + ks + q * 8);
                acc[t] = __builtin_amdgcn_mfma_f32_16x16x32_bf16(a, b, acc[t], 0, 0, 0);
            }
        }
        __syncthreads();

        // C/D: col = lane&15, row = (lane>>4)*4 + reg
        #pragma unroll
        for (int t = 0; t < 8; ++t)
            #pragma unroll
            for (int r = 0; r < 4; ++r)
                hs[(wave * 16 + q * 4 + r) * HPAD + t * 16 + m] = acc[t][r];
        __syncthreads();

        for (int i = tid * 4; i < 64 * HC; i += 1024) {
            int r = i >> 7, c = i & 127;
            if (row0 + r < N_NODES) {
                float4 v = *(const float4*)(hs + r * HPAD + c);
                uint32_t lo = (uint32_t)f2bf(v.x) | ((uint32_t)f2bf(v.y) << 16);
                uint32_t hi = (uint32_t)f2bf(v.z) | ((uint32_t)f2bf(v.w) << 16);
                *(uint2*)(hb + (size_t)(row0 + r) * HC + c) = make_uint2(lo, hi);
            }
        }
        {
            int r = tid >> 2, hd = tid & 3;
            if (row0 + r < N_NODES) {
                float s = 0.f, d = 0.f;
                #pragma unroll
                for (int j = 0; j < 32; ++j) {
                    float v = hs[r * HPAD + hd * 32 + j];
                    s = fmaf(v, att_s[hd * 32 + j], s);
                    d = fmaf(v, att_d[hd * 32 + j], d);
                }
                a_src[(row0 + r) * NHEAD + hd] = s;
                a_dst[(row0 + r) * NHEAD + hd] = d;
            }
        }
    } else {
        // ---------------- p3: bin edges into fixed-stride bucket regions ----
        int* hist = (int*)smem;
        int* lcur = hist + NBUK;
        for (int i = tid; i < NBUK; i += 256) hist[i] = 0;
        __syncthreads();

        uint32_t wreg[EPT];
        const int base = (blockIdx.x - K1_NB) * CHUNK;
        #pragma unroll
        for (int k = 0; k < EPT; ++k) {
            int e = base + k * 256 + tid;
            uint32_t word = 0xFFFFFFFFu;
            if (e < TOT_E) {
                int src, dst;
                if (e < N_EDGES) { src = ei[e]; dst = ei[N_EDGES + e]; }
                else             { src = e - N_EDGES; dst = src; }
                int b = dst >> SHIFT;
                word = (uint32_t)src | ((uint32_t)(dst & (BSZ - 1)) << 16)
                     | ((uint32_t)b << 23);
                atomicAdd(&hist[b], 1);
            }
            wreg[k] = word;
        }
        __syncthreads();
        for (int i = tid; i < NBUK; i += 256) {
            int c = hist[i];
            lcur[i] = c ? atomicAdd(&gcur[i], c) : 0;   // within-bucket base
        }
        __syncthreads();
        #pragma unroll
        for (int k = 0; k < EPT; ++k) {
            uint32_t word = wreg[k];
            if (word != 0xFFFFFFFFu) {
                int b = (int)(word >> 23);
                int pos = atomicAdd(&lcur[b], 1);
                if (pos < CAP) binned[(size_t)b * CAP + pos] = word;
            }
        }
    }
}

// ---------------------------------------------------------------------------
// Q4 (fused p4+k6): 4 quarter-blocks per bucket. Stream the bucket's binned
// region, keep this quarter's edges in LDS (append -> count -> scan ->
// regroup), then gather.
//
// v2: 512-thread blocks (8 waves), ONE pass, 4 nodes per wave.
// Rationale (R1 counters): grid 1564 x 4 waves = 6.1 blocks/CU -> occupancy
// capped at 45%, latency-bound (VALUBusy 35%, HBM 37%). With 512 threads,
// 4 resident blocks/CU = 32 waves/CU (100% of wave budget) while the math
// per lane is unchanged: 16 lanes/node, 8 ch/lane, uint4 h-row loads,
// srcs read 4-at-a-time via one aligned ds_read_b64.
// ---------------------------------------------------------------------------
__global__ __launch_bounds__(512) void q4_agg(const uint32_t* __restrict__ binned,
                                              const int* __restrict__ gcur,
                                              const uint32_t* __restrict__ hb32,
                                              const float* __restrict__ a_src,
                                              const float* __restrict__ a_dst,
                                              const float* __restrict__ bias,
                                              uint32_t* __restrict__ actb) {
    __shared__ uint32_t ewb[QCAP];       // 7 KB: unordered append of this quarter's edges
    __shared__ uint16_t ew2[QCAP * 2];   // 7 KB: srcs grouped by local node (2x pad for safe overread)
    __shared__ int ncnt[32], nbeg[32], ncur[32];
    __shared__ int tot;
    const int b   = blockIdx.x >> 2;
    const int sub = blockIdx.x & 3;
    const int tid = threadIdx.x;

    int cnt = gcur[b];
    if (cnt > CAP) cnt = CAP;
    if (tid == 0) tot = 0;
    if (tid < 32) ncnt[tid] = 0;
    __syncthreads();

    const uint32_t* bb = binned + (size_t)b * CAP;
    for (int i = tid; i < cnt; i += 512) {
        uint32_t word = bb[i];
        int dl = (word >> 16) & 127;
        if ((dl >> 5) == sub) {
            int pos = atomicAdd(&tot, 1);
            if (pos < QCAP) ewb[pos] = word;
            atomicAdd(&ncnt[dl & 31], 1);
        }
    }
    __syncthreads();
    int T = tot;
    if (T > QCAP) T = QCAP;

    if (tid < 32) {                       // inclusive scan of counts padded to x4
        int v  = ncnt[tid];
        int v4 = (v + 3) & ~3;            // pad region so nbeg is 8B-aligned (b64 reads)
        int inc = v4;
        #pragma unroll
        for (int d = 1; d < 32; d <<= 1) {
            int t = __shfl_up(inc, d, 64);
            if (tid >= d) inc += t;
        }
        nbeg[tid] = inc - v4;
        ncur[tid] = inc - v4;
    }
    __syncthreads();
    for (int i = tid; i < T; i += 512) {
        uint32_t word = ewb[i];
        int ln  = (word >> 16) & 31;
        int pos = atomicAdd(&ncur[ln], 1);
        ew2[pos] = (uint16_t)(word & 0xFFFFu);    // src only (< 50000 fits u16)
    }
    __syncthreads();

    // gather: wave w handles nodes w*4 .. w*4+3, one node per 16-lane group
    const int wave = tid >> 6;           // 0..7
    const int lane = tid & 63;
    const int g    = lane >> 4;          // node sub-group within wave
    const int sl   = lane & 15;          // channel sublane: ch [sl*8, sl*8+8)
    const int head = sl >> 2;
    const char*  hb8 = (const char*)hb32 + sl * 16;
    const float* ash = a_src + head;
    const float4 bA = *(const float4*)(bias + sl * 8);
    const float4 bB = *(const float4*)(bias + sl * 8 + 4);

    const int ln   = wave * 4 + g;       // 0..31
    const int node = b * BSZ + sub * 32 + ln;
    const int myc  = ncnt[ln];
    const int p0   = nbeg[ln];
    int m1   = max(myc, __shfl_xor(myc, 16, 64));
    int maxc = max(m1,  __shfl_xor(m1, 32, 64));
    // a_dst overread for OOB node stays inside workspace; value unused (w=0)
    const float ad = a_dst[min(node, N_NODES - 1) * NHEAD + head];

    float l = 0.f;
    float acc[8];
    #pragma unroll
    for (int j = 0; j < 8; ++j) acc[j] = 0.f;

    for (int i = 0; i < maxc; i += 4) {
        u16x4 sv = *(const u16x4*)(&ew2[p0 + i]);   // 1 ds_read_b64 = 4 srcs
        const int s0 = sv[0], s1 = sv[1], s2 = sv[2], s3 = sv[3];
        float as0 = ash[s0 * NHEAD];
        float as1 = ash[s1 * NHEAD];
        float as2 = ash[s2 * NHEAD];
        float as3 = ash[s3 * NHEAD];
        uint4 h0 = *(const uint4*)(hb8 + ((uint32_t)s0 << 8));
        uint4 h1 = *(const uint4*)(hb8 + ((uint32_t)s1 << 8));
        uint4 h2 = *(const uint4*)(hb8 + ((uint32_t)s2 << 8));
        uint4 h3 = *(const uint4*)(hb8 + ((uint32_t)s3 << 8));
        float e0 = as0 + ad, e1 = as1 + ad, e2 = as2 + ad, e3 = as3 + ad;
        e0 = fmaxf(e0, 0.2f * e0);
        e1 = fmaxf(e1, 0.2f * e1);
        e2 = fmaxf(e2, 0.2f * e2);
        e3 = fmaxf(e3, 0.2f * e3);
        float w0 = __expf(e0), w1 = __expf(e1);
        float w2 = __expf(e2), w3 = __expf(e3);
        w0 = (i + 0 < myc) ? w0 : 0.f;
        w1 = (i + 1 < myc) ? w1 : 0.f;
        w2 = (i + 2 < myc) ? w2 : 0.f;
        w3 = (i + 3 < myc) ? w3 : 0.f;
        l += (w0 + w1) + (w2 + w3);
        acc[0] = fmaf(w0, bf_lo(h0.x), acc[0]); acc[0] = fmaf(w1, bf_lo(h1.x), acc[0]);
        acc[0] = fmaf(w2, bf_lo(h2.x), acc[0]); acc[0] = fmaf(w3, bf_lo(h3.x), acc[0]);
        acc[1] = fmaf(w0, bf_hi(h0.x), acc[1]); acc[1] = fmaf(w1, bf_hi(h1.x), acc[1]);
        acc[1] = fmaf(w2, bf_hi(h2.x), acc[1]); acc[1] = fmaf(w3, bf_hi(h3.x), acc[1]);
        acc[2] = fmaf(w0, bf_lo(h0.y), acc[2]); acc[2] = fmaf(w1, bf_lo(h1.y), acc[2]);
        acc[2] = fmaf(w2, bf_lo(h2.y), acc[2]); acc[2] = fmaf(w3, bf_lo(h3.y), acc[2]);
        acc[3] = fmaf(w0, bf_hi(h0.y), acc[3]); acc[3] = fmaf(w1, bf_hi(h1.y), acc[3]);
        acc[3] = fmaf(w2, bf_hi(h2.y), acc[3]); acc[3] = fmaf(w3, bf_hi(h3.y), acc[3]);
        acc[4] = fmaf(w0, bf_lo(h0.z), acc[4]); acc[4] = fmaf(w1, bf_lo(h1.z), acc[4]);
        acc[4] = fmaf(w2, bf_lo(h2.z), acc[4]); acc[4] = fmaf(w3, bf_lo(h3.z), acc[4]);
        acc[5] = fmaf(w0, bf_hi(h0.z), acc[5]); acc[5] = fmaf(w1, bf_hi(h1.z), acc[5]);
        acc[5] = fmaf(w2, bf_hi(h2.z), acc[5]); acc[5] = fmaf(w3, bf_hi(h3.z), acc[5]);
        acc[6] = fmaf(w0, bf_lo(h0.w), acc[6]); acc[6] = fmaf(w1, bf_lo(h1.w), acc[6]);
        acc[6] = fmaf(w2, bf_lo(h2.w), acc[6]); acc[6] = fmaf(w3, bf_lo(h3.w), acc[6]);
        acc[7] = fmaf(w0, bf_hi(h0.w), acc[7]); acc[7] = fmaf(w1, bf_hi(h1.w), acc[7]);
        acc[7] = fmaf(w2, bf_hi(h2.w), acc[7]); acc[7] = fmaf(w3, bf_hi(h3.w), acc[7]);
    }

    if (node < N_NODES) {
        const float inv = 1.f / l;        // self loop => l > 0
        float o[8];
        o[0] = fmaf(acc[0], inv, bA.x); o[1] = fmaf(acc[1], inv, bA.y);
        o[2] = fmaf(acc[2], inv, bA.z); o[3] = fmaf(acc[3], inv, bA.w);
        o[4] = fmaf(acc[4], inv, bB.x); o[5] = fmaf(acc[5], inv, bB.y);
        o[6] = fmaf(acc[6], inv, bB.z); o[7] = fmaf(acc[7], inv, bB.w);
        #pragma unroll
        for (int j = 0; j < 8; ++j)
            o[j] = (o[j] > 0.f) ? o[j] : (__expf(o[j]) - 1.f);
        uint4 pk;
        pk.x = (uint32_t)f2bf(o[0]) | ((uint32_t)f2bf(o[1]) << 16);
        pk.y = (uint32_t)f2bf(o[2]) | ((uint32_t)f2bf(o[3]) << 16);
        pk.z = (uint32_t)f2bf(o[4]) | ((uint32_t)f2bf(o[5]) << 16);
        pk.w = (uint32_t)f2bf(o[6]) | ((uint32_t)f2bf(o[7]) << 16);
        *(uint4*)(actb + (size_t)node * 64 + sl * 4) = pk;
    }
}

// ---------------------------------------------------------------------------
// K7: out = act @ lin_W + lin_b   [N,128] @ [128,64] via MFMA.
// act (actb) is already exact bf16; lin_W is split hi+lo bf16 so the product
// keeps f32 accuracy (hi+lo error ~2^-17).
// ---------------------------------------------------------------------------
__global__ __launch_bounds__(256) void k7_out(const uint16_t* __restrict__ ab,
                                              const uint16_t* __restrict__ lwt,
                                              const float* __restrict__ linb,
                                              float* __restrict__ out) {
    __shared__ uint16_t as_[64][136];    // 64 rows x 128 bf16 (+8 pad; 272B row = 17x16B)
    const int tid  = threadIdx.x;
    const int row0 = blockIdx.x * 64;

    for (int i = tid; i < 64 * 16; i += 256) {   // 16 KB stage, 4 uint4/thread
        int r = i >> 4, cw = i & 15;
        int node = row0 + r;
        uint4 v = make_uint4(0, 0, 0, 0);
        if (node < N_NODES) v = *(const uint4*)(ab + (size_t)node * HC + cw * 8);
        *(uint4*)(&as_[r][cw * 8]) = v;
    }
    __syncthreads();

    const int wave = tid >> 6;
    const int lane = tid & 63;
    const int m    = lane & 15;
    const int q    = lane >> 4;
    const uint16_t* lwlo = lwt + OUT_DIM * HC;

    f32x4 acc[4];
    #pragma unroll
    for (int t = 0; t < 4; ++t) acc[t] = (f32x4){0.f, 0.f, 0.f, 0.f};

    const int arow = wave * 16 + m;
    #pragma unroll
    for (int ks = 0; ks < HC; ks += 32) {
        bf16x8 a = *(const bf16x8*)(&as_[arow][ks + q * 8]);
        #pragma unroll
        for (int t = 0; t < 4; ++t) {
            bf16x8 bh = *(const bf16x8*)(lwt  + (size_t)(t * 16 + m) * HC + ks + q * 8);
            bf16x8 bl = *(const bf16x8*)(lwlo + (size_t)(t * 16 + m) * HC + ks + q * 8);
            acc[t] = __builtin_amdgcn_mfma_f32_16x16x32_bf16(a, bh, acc[t], 0, 0, 0);
            acc[t] = __builtin_amdgcn_mfma_f32_16x16x32_bf16(a, bl, acc[t], 0, 0, 0);
        }
    }

    // C/D: col = lane&15, row = (lane>>4)*4 + reg
    const int grow = row0 + wave * 16 + q * 4;
    #pragma unroll
    for (int t = 0; t < 4; ++t) {
        const int col = t * 16 + m;
        const float lb = linb[col];
        #pragma unroll
        for (int r = 0; r < 4; ++r)
            if (grow + r < N_NODES)
                out[(size_t)(grow + r) * OUT_DIM + col] = acc[t][r] + lb;
    }
}

// ---------------------------------------------------------------------------
extern "C" void kernel_launch(void* const* d_in, const int* in_sizes, int n_in,
                              void* d_out, int out_size, void* d_ws, size_t ws_size,
                              hipStream_t stream) {
    (void)in_sizes; (void)n_in; (void)out_size; (void)ws_size;
    const float* x       = (const float*)d_in[0];
    const int*   ei      = (const int*)d_in[1];
    const float* W       = (const float*)d_in[2];
    const float* att_src = (const float*)d_in[3];
    const float* att_dst = (const float*)d_in[4];
    const float* bias    = (const float*)d_in[5];
    const float* linW    = (const float*)d_in[6];
    const float* linb    = (const float*)d_in[7];
    float*       out     = (float*)d_out;

    char*  ws  = (char*)d_ws;
    size_t off = 0;
    auto alloc = [&](size_t bytes) -> void* {
        void* p = ws + off;
        off += (bytes + 255) & ~(size_t)255;
        return p;
    };
    uint16_t* hb     = (uint16_t*)alloc((size_t)N_NODES * HC * 2);
    uint16_t* wt     = (uint16_t*)alloc((size_t)HC * IN_DIM * 2);
    uint32_t* actb   = (uint32_t*)alloc((size_t)N_NODES * 64 * 4);
    float*    a_src  = (float*)alloc((size_t)N_NODES * NHEAD * 4);
    float*    a_dst  = (float*)alloc((size_t)N_NODES * NHEAD * 4);
    int*      gcur   = (int*)alloc((size_t)NBUK * 4);
    uint32_t* binned = (uint32_t*)alloc((size_t)NBUK * CAP * 4);
    uint16_t* lwt    = (uint16_t*)alloc((size_t)2 * OUT_DIM * HC * 2);

    w2bf<<<W2_GEMM_BLK + W2_LIN_BLK, 256, 0, stream>>>(W, linW, wt, lwt, gcur);
    k1p3<<<K1_NB + NCHUNK, 256, 0, stream>>>(x, wt, att_src, att_dst,
                                             hb, a_src, a_dst,
                                             ei, gcur, binned);
    q4_agg<<<NBUK * 4, 512, 0, stream>>>(binned, gcur, (const uint32_t*)hb,
                                         a_src, a_dst, bias, actb);
    k7_out<<<(N_NODES + 63) / 64, 256, 0, stream>>>((const uint16_t*)actb, lwt,
                                                    linb, out);
}